// Round 1
// baseline (176.555 us; speedup 1.0000x reference)
//
#include <hip/hip_runtime.h>

// Problem: out0 = cumsum(z, axis=0), z fp32 [8192, 64, 128] -> rows=8192,
// cols=64*128=8192 contiguous per row. out1 = previous_loss (1 float) at
// d_out[67108864].

constexpr int NROWS = 8192;
constexpr int NCOLS = 8192;          // 64*128 contiguous floats per row
constexpr int NCOL4 = NCOLS / 4;     // 2048 float4 per row
constexpr int KCH   = 128;           // row chunks
constexpr int RR    = NROWS / KCH;   // 64 rows per chunk
constexpr int TPB   = 256;
constexpr int CT    = NCOL4 / TPB;   // 8 column tiles of 1024 cols

// Pass 1: per-column sums of each row-chunk -> part[KCH][NCOLS]
__global__ __launch_bounds__(TPB) void k_partial(const float4* __restrict__ z,
                                                 float4* __restrict__ part) {
    const int tile  = blockIdx.x & (CT - 1);
    const int chunk = blockIdx.x >> 3;            // / CT
    const int c4    = tile * TPB + threadIdx.x;   // float4 column index
    const float4* p = z + (size_t)chunk * RR * NCOL4 + c4;
    float4 a = make_float4(0.f, 0.f, 0.f, 0.f);
    #pragma unroll 8
    for (int r = 0; r < RR; ++r) {
        float4 v = p[(size_t)r * NCOL4];
        a.x += v.x; a.y += v.y; a.z += v.z; a.w += v.w;
    }
    part[(size_t)chunk * NCOL4 + c4] = a;
}

// Pass 2: in-place serial EXCLUSIVE scan over the KCH chunk sums, per column.
// Also forwards previous_loss to the output tail.
__global__ __launch_bounds__(TPB) void k_scan(float* __restrict__ part,
                                              const float* __restrict__ prev,
                                              float* __restrict__ out_tail) {
    const int c = blockIdx.x * TPB + threadIdx.x; // 0..8191
    float run = 0.f;
    #pragma unroll 4
    for (int k = 0; k < KCH; ++k) {
        const size_t i = (size_t)k * NCOLS + c;
        float v = part[i];
        part[i] = run;
        run += v;
    }
    if (blockIdx.x == 0 && threadIdx.x == 0) out_tail[0] = prev[0];
}

// Pass 3: re-read z, seed with exclusive chunk offset, write inclusive cumsum.
__global__ __launch_bounds__(TPB) void k_apply(const float4* __restrict__ z,
                                               const float4* __restrict__ part,
                                               float4* __restrict__ out) {
    const int tile  = blockIdx.x & (CT - 1);
    const int chunk = blockIdx.x >> 3;
    const int c4    = tile * TPB + threadIdx.x;
    float4 a = part[(size_t)chunk * NCOL4 + c4];
    const float4* p = z   + (size_t)chunk * RR * NCOL4 + c4;
    float4*       q = (float4*)out + (size_t)chunk * RR * NCOL4 + c4;
    #pragma unroll 4
    for (int r = 0; r < RR; ++r) {
        float4 v = p[(size_t)r * NCOL4];
        a.x += v.x; a.y += v.y; a.z += v.z; a.w += v.w;
        q[(size_t)r * NCOL4] = a;
    }
}

extern "C" void kernel_launch(void* const* d_in, const int* in_sizes, int n_in,
                              void* d_out, int out_size, void* d_ws, size_t ws_size,
                              hipStream_t stream) {
    const float4* z    = (const float4*)d_in[0];
    const float*  prev = (const float*)d_in[1];
    float*        out  = (float*)d_out;
    float*        part = (float*)d_ws;   // KCH*NCOLS floats = 4 MiB

    k_partial<<<KCH * CT, TPB, 0, stream>>>(z, (float4*)part);
    k_scan<<<NCOLS / TPB, TPB, 0, stream>>>(part, prev, out + (size_t)NROWS * NCOLS);
    k_apply<<<KCH * CT, TPB, 0, stream>>>(z, (const float4*)part, (float4*)out);
}